// Round 7
// baseline (538.936 us; speedup 1.0000x reference)
//
#include <hip/hip_runtime.h>

typedef unsigned short u16;
typedef __attribute__((ext_vector_type(8))) short short8;   // 8 x bf16 (4 VGPRs)
typedef __attribute__((ext_vector_type(4))) float f32x4;

#define HALFN 2016

__device__ __forceinline__ u16 f2b_rn(float x) {         // round-nearest-even
    union { float f; unsigned u; } v; v.f = x;
    unsigned r = v.u + 0x7FFFu + ((v.u >> 16) & 1u);
    return (u16)(r >> 16);
}

__device__ __forceinline__ void gll16(const void* g, void* s) {
    __builtin_amdgcn_global_load_lds(
        (const __attribute__((address_space(1))) unsigned int*)g,
        (__attribute__((address_space(3))) unsigned int*)s, 16, 0, 0);
}

// Hand-rolled grid barrier (cg::grid_group::sync equivalent).  Counter is
// zeroed by the preceding ln_prep launch each call.  All 512 blocks are
// co-resident by construction (launch_bounds(256,2) => 2 blocks/CU x 256 CU).
__device__ __forceinline__ void gbar(unsigned* c, unsigned target) {
    __threadfence();                 // release my stores (agent scope)
    __syncthreads();
    if (threadIdx.x == 0) {
        __hip_atomic_fetch_add(c, 1u, __ATOMIC_RELEASE, __HIP_MEMORY_SCOPE_AGENT);
        while (__hip_atomic_load(c, __ATOMIC_ACQUIRE, __HIP_MEMORY_SCOPE_AGENT) < target)
            __builtin_amdgcn_s_sleep(2);
    }
    __syncthreads();
    __threadfence();                 // acquire: discard stale cached lines
}

// ---------------------------------------------------------------------------
// Kernel 1 (regular): blocks 0..8191 LayerNorm -> Xh (RN bf16);
// blocks 8192..8255 prep Pw (transpose, RN bf16); block 8192 zeroes barriers.
// ---------------------------------------------------------------------------
__global__ __launch_bounds__(256) void ln_prep(const float* __restrict__ x1,
                                               const float* __restrict__ x2,
                                               const float* __restrict__ gamma,
                                               const float* __restrict__ beta,
                                               const float* __restrict__ proj,
                                               u16* __restrict__ Xh,
                                               u16* __restrict__ Pwh,
                                               unsigned* __restrict__ cnt) {
    __shared__ float ls[8], lq[8];
    __shared__ float tile[64][65];
    const int bid = blockIdx.x, t = threadIdx.x;

    if (bid < 8192) {
        const float* src = (bid < 4096) ? (x1 + (size_t)bid * 512)
                                        : (x2 + (size_t)(bid - 4096) * 512);
        float2 v = *(const float2*)&src[t * 2];
        float s  = v.x + v.y;
        float sq = v.x * v.x + v.y * v.y;
        #pragma unroll
        for (int off = 32; off > 0; off >>= 1) {
            s  += __shfl_down(s, off);
            sq += __shfl_down(sq, off);
        }
        int wave = t >> 6, lane = t & 63;
        if (lane == 0) { ls[wave] = s; lq[wave] = sq; }
        __syncthreads();
        if (t == 0) {
            float Sm = 0.f, Q = 0.f;
            #pragma unroll
            for (int i = 0; i < 4; i++) { Sm += ls[i]; Q += lq[i]; }
            float mu  = Sm * (1.0f / 512.0f);
            float var = Q * (1.0f / 512.0f) - mu * mu;
            ls[4] = mu;
            lq[4] = rsqrtf(var + 1e-5f);
        }
        __syncthreads();
        float mu = ls[4], rs = lq[4];
        float2 g  = *(const float2*)&gamma[t * 2];
        float2 bb = *(const float2*)&beta[t * 2];
        float o0 = (v.x - mu) * rs * g.x + bb.x;
        float o1 = (v.y - mu) * rs * g.y + bb.y;
        ushort2 H; H.x = f2b_rn(o0); H.y = f2b_rn(o1);
        *(ushort2*)&Xh[(size_t)bid * 512 + t * 2] = H;
    } else {
        const int id = bid - 8192;
        if (id == 0 && t < 8) cnt[t] = 0;       // zero grid-barrier counters
        const int n = id >> 3, c0 = (id & 7) * 64;
        #pragma unroll
        for (int i = 0; i < 4; i++) {
            int flat = i * 256 + t;
            int c = flat >> 4, k4 = (flat & 15) * 4;
            float4 v = *(const float4*)&proj[(size_t)n * 32768 + (size_t)(c0 + c) * 64 + k4];
            tile[c][k4 + 0] = v.x; tile[c][k4 + 1] = v.y;
            tile[c][k4 + 2] = v.z; tile[c][k4 + 3] = v.w;
        }
        __syncthreads();
        #pragma unroll
        for (int i = 0; i < 16; i++) {
            int flat = i * 256 + t;
            int k = flat >> 6, c = flat & 63;
            Pwh[(size_t)(n * 64 + k) * 512 + c0 + c] = f2b_rn(tile[c][k]);
        }
    }
}

// ---------------------------------------------------------------------------
// MFMA single-product bf16 GEMM core: TMxTN tile, BK=32, K=512, ld=512.
// XOR-swizzled LDS, gll16 staging, conflict-free ds_read_b128 fragments.
// ---------------------------------------------------------------------------
template<int TM, int TN>
__device__ __forceinline__ void gemm_core_a1b1(const u16* __restrict__ A,
                                               const u16* __restrict__ B,
                                               int m0, int n0, u16* lds,
                                               f32x4 (&acc)[TM / 32][TN / 32]) {
    constexpr int MI = TM / 32, NI = TN / 32;
    constexpr int LA = TM * 32;
    const int t = threadIdx.x;
    const int lane = t & 63;
    const int w = t >> 6, wm = w & 1, wn = w >> 1;
    const int fr = lane & 15, q = lane >> 4;

    int aoff[MI], boff[NI];
    #pragma unroll
    for (int i = 0; i < MI; i++) {
        int r = wm * (TM / 2) + i * 16 + fr;
        aoff[i] = r * 32 + ((q ^ ((r >> 1) & 3)) * 8);
    }
    #pragma unroll
    for (int j = 0; j < NI; j++) {
        int r = wn * (TN / 2) + j * 16 + fr;
        boff[j] = r * 32 + ((q ^ ((r >> 1) & 3)) * 8);
    }

    for (int kt = 0; kt < 512; kt += 32) {
        #pragma unroll
        for (int p = 0; p < TM / 64; p++) {
            int o = p * 4096 + t * 16;
            int r = o >> 6;
            int kc = ((o >> 4) & 3) ^ ((r >> 1) & 3);
            gll16(A + (size_t)(m0 + r) * 512 + kt + kc * 8, lds + (o >> 1));
        }
        #pragma unroll
        for (int p = 0; p < TN / 64; p++) {
            int o = p * 4096 + t * 16;
            int r = o >> 6;
            int kc = ((o >> 4) & 3) ^ ((r >> 1) & 3);
            gll16(B + (size_t)(n0 + r) * 512 + kt + kc * 8, lds + LA + (o >> 1));
        }
        __syncthreads();
        short8 af[MI], bf[NI];
        #pragma unroll
        for (int i = 0; i < MI; i++)
            af[i] = *(const short8*)(lds + aoff[i]);
        #pragma unroll
        for (int j = 0; j < NI; j++)
            bf[j] = *(const short8*)(lds + LA + boff[j]);
        #pragma unroll
        for (int i = 0; i < MI; i++)
            #pragma unroll
            for (int j = 0; j < NI; j++)
                acc[i][j] = __builtin_amdgcn_mfma_f32_16x16x32_bf16(af[i], bf[j], acc[i][j], 0, 0, 0);
        __syncthreads();
    }
}

// ---------------------------------------------------------------------------
// Mega-kernel (regular launch + manual grid barrier), grid 512 x 256:
//  P  (512): PP = Xn @ Pw -> PPh + PPT1h/PPT2h; blocks 0..15 zero S first.
//  S  (256): G = P2^T P1 (MFMA over v, atomic reduce into S).
//  TU (128): build metric M, T = M@G in LDS, U-chunk -> UTh (RN bf16).
//  O  (512): out = PP1 @ Ucat + bias.
// ---------------------------------------------------------------------------
__global__ __launch_bounds__(256, 2) void mega(const u16* __restrict__ Xh,
                                               const u16* __restrict__ Pwh,
                                               u16* __restrict__ PPh,
                                               u16* __restrict__ PPT1h,
                                               u16* __restrict__ PPT2h,
                                               float* __restrict__ S,
                                               const float* __restrict__ halves,
                                               const float* __restrict__ diagonals,
                                               const float* __restrict__ Wm,
                                               u16* __restrict__ UTh,
                                               const float* __restrict__ bias,
                                               float* __restrict__ out,
                                               unsigned* __restrict__ cnt) {
    union Sh {
        u16 g[6144];                                  // 12,288 B (gemm staging)
        struct { float Ms[64][65]; float Gs[64][68]; float Ts[64][68]; } tu;  // 51,456 B
    };
    __shared__ Sh sm;
    const int bid = blockIdx.x, t = threadIdx.x;
    const int lane = t & 63, w = t >> 6, wm = w & 1, wn = w >> 1;
    const int fr = lane & 15, q = lane >> 4;

    // ================= phase P: zero S + proj GEMM =================
    if (bid < 16) {
        float4 z = {0.f, 0.f, 0.f, 0.f};
        float* Sb = S + bid * 4096;
        #pragma unroll
        for (int i = 0; i < 4; i++)
            *(float4*)&Sb[(i * 256 + t) * 4] = z;
    }
    {
        f32x4 acc[4][2] = {};
        const int m0 = (bid >> 3) * 128, n0 = (bid & 7) * 64;
        gemm_core_a1b1<128, 64>(Xh, Pwh, m0, n0, sm.g, acc);
        const int src2 = (m0 >= 4096);
        const int b = (m0 & 4095) >> 11;
        const int v00 = m0 & 2047;
        #pragma unroll
        for (int i = 0; i < 4; i++) {
            int mloc = wm * 64 + i * 16 + q * 4;
            int v = v00 + mloc;
            #pragma unroll
            for (int j = 0; j < 2; j++) {
                int n = n0 + wn * 32 + j * 16 + fr;
                u16 hs[4];
                #pragma unroll
                for (int r = 0; r < 4; r++) hs[r] = f2b_rn(acc[i][j][r]);
                ushort4 hv; hv.x = hs[0]; hv.y = hs[1]; hv.z = hs[2]; hv.w = hs[3];
                if (!src2) {
                    #pragma unroll
                    for (int r = 0; r < 4; r++)
                        PPh[(size_t)(m0 + mloc + r) * 512 + n] = hs[r];
                    *(ushort4*)&PPT1h[((size_t)(b * 512 + n)) * 2048 + v] = hv;
                } else {
                    *(ushort4*)&PPT2h[((size_t)(b * 512 + n)) * 2048 + v] = hv;
                }
            }
        }
    }
    gbar(&cnt[0], 512);

    // ================= phase S: G = P2^T P1 =================
    if (bid < 256) {
        const int bn = bid >> 4, b = bn >> 3, n = bn & 7;
        const u16* A = PPT2h + ((size_t)(b * 512 + n * 64)) * 2048;
        const u16* B = PPT1h + ((size_t)(b * 512 + n * 64)) * 2048;
        u16* lds = sm.g;

        int aoff[2], boff[2];
        #pragma unroll
        for (int i = 0; i < 2; i++) {
            int r = wm * 32 + i * 16 + fr;
            aoff[i] = r * 32 + ((q ^ ((r >> 1) & 3)) * 8);
        }
        #pragma unroll
        for (int j = 0; j < 2; j++) {
            int r = wn * 32 + j * 16 + fr;
            boff[j] = r * 32 + ((q ^ ((r >> 1) & 3)) * 8);
        }
        const int o = t * 16;
        const int rr = o >> 6;
        const int kc = ((o >> 4) & 3) ^ ((rr >> 1) & 3);
        const int le = o >> 1;

        f32x4 acc[2][2] = {};
        const int k0 = (bid & 15) * 128;
        for (int kt = k0; kt < k0 + 128; kt += 32) {
            size_t g = (size_t)rr * 2048 + kt + kc * 8;
            gll16(A + g, lds + le);
            gll16(B + g, lds + 2048 + le);
            __syncthreads();
            short8 af[2], bf[2];
            #pragma unroll
            for (int i = 0; i < 2; i++) af[i] = *(const short8*)(lds + aoff[i]);
            #pragma unroll
            for (int j = 0; j < 2; j++) bf[j] = *(const short8*)(lds + 2048 + boff[j]);
            #pragma unroll
            for (int i = 0; i < 2; i++)
                #pragma unroll
                for (int j = 0; j < 2; j++)
                    acc[i][j] = __builtin_amdgcn_mfma_f32_16x16x32_bf16(af[i], bf[j], acc[i][j], 0, 0, 0);
            __syncthreads();
        }
        float* Sb = S + (size_t)bn * 4096;
        #pragma unroll
        for (int i = 0; i < 2; i++) {
            int jrow = wm * 32 + i * 16 + q * 4;
            #pragma unroll
            for (int j = 0; j < 2; j++) {
                int kk = wn * 32 + j * 16 + fr;
                #pragma unroll
                for (int r = 0; r < 4; r++)
                    atomicAdd(&Sb[(jrow + r) * 64 + kk], acc[i][j][r]);
            }
        }
    }
    gbar(&cnt[1], 512);

    // ================= phase TU: M-build, T = M@G, U-chunk =================
    if (bid < 128) {
        const int bn = bid >> 3, b = bn >> 3, n = bn & 7, cy = bid & 7;
        for (int idx = t; idx < 4096; idx += 256) {
            int r = idx >> 6, c = idx & 63;
            float val;
            if (r == c) {
                val = diagonals[n * 64 + r];
            } else {
                int rr = (r < c) ? r : c;
                int cc = (r < c) ? c : r;
                int h = rr * 63 - (rr * (rr - 1)) / 2 + (cc - rr - 1);
                val = halves[n * HALFN + h];
            }
            sm.tu.Ms[r][c] = val;
        }
        for (int idx = t; idx < 4096; idx += 256)
            sm.tu.Gs[idx >> 6][idx & 63] = S[(size_t)bn * 4096 + idx];
        __syncthreads();

        {   // T = M @ G : thread (k = t&63) computes chunk lq = t>>6 (16 cols)
            const int k = t & 63, lq = t >> 6;
            float a[16] = {};
            for (int j = 0; j < 64; j++) {
                float m = sm.tu.Ms[k][j];
                const float* gp = &sm.tu.Gs[j][lq * 16];
                #pragma unroll
                for (int u4 = 0; u4 < 4; u4++) {
                    float4 g4 = *(const float4*)&gp[u4 * 4];
                    a[u4 * 4 + 0] = fmaf(m, g4.x, a[u4 * 4 + 0]);
                    a[u4 * 4 + 1] = fmaf(m, g4.y, a[u4 * 4 + 1]);
                    a[u4 * 4 + 2] = fmaf(m, g4.z, a[u4 * 4 + 2]);
                    a[u4 * 4 + 3] = fmaf(m, g4.w, a[u4 * 4 + 3]);
                }
            }
            int pos = (lq ^ (k & 3)) * 16;             // swizzled chunk slot
            #pragma unroll
            for (int u4 = 0; u4 < 4; u4++) {
                float4 v4 = {a[u4 * 4 + 0], a[u4 * 4 + 1], a[u4 * 4 + 2], a[u4 * 4 + 3]};
                *(float4*)&sm.tu.Ts[k][pos + u4 * 4] = v4;
            }
        }
        __syncthreads();

        const int k2 = t & 63, cgp = t >> 6;
        const int c0 = cy * 64 + cgp * 16;
        float uacc[16] = {};
        #pragma unroll
        for (int kkc = 0; kkc < 4; kkc++) {
            const float* tp = &sm.tu.Ts[k2][(kkc ^ (k2 & 3)) * 16];
            float ts[16];
            #pragma unroll
            for (int u = 0; u < 4; u++) {
                float4 t4 = *(const float4*)&tp[u * 4];
                ts[u * 4 + 0] = t4.x; ts[u * 4 + 1] = t4.y;
                ts[u * 4 + 2] = t4.z; ts[u * 4 + 3] = t4.w;
            }
            #pragma unroll
            for (int i = 0; i < 16; i++) {
                const float* wrow = &Wm[(size_t)(c0 + i) * 512 + n * 64 + kkc * 16];
                #pragma unroll
                for (int u = 0; u < 4; u++) {
                    float4 w4 = *(const float4*)&wrow[u * 4];
                    uacc[i] = fmaf(ts[u * 4 + 0], w4.x, uacc[i]);
                    uacc[i] = fmaf(ts[u * 4 + 1], w4.y, uacc[i]);
                    uacc[i] = fmaf(ts[u * 4 + 2], w4.z, uacc[i]);
                    uacc[i] = fmaf(ts[u * 4 + 3], w4.w, uacc[i]);
                }
            }
        }
        #pragma unroll
        for (int i = 0; i < 16; i++)
            UTh[(size_t)b * 262144 + (size_t)(c0 + i) * 512 + n * 64 + k2] = f2b_rn(uacc[i]);
    }
    gbar(&cnt[2], 512);

    // ================= phase O: out = PP1 @ Ucat + bias =================
    {
        const int b = bid >> 8, my = (bid >> 3) & 31, nx = bid & 7;
        const u16* A = PPh + (size_t)b * 2048 * 512;
        const u16* B = UTh + (size_t)b * 512 * 512;
        f32x4 acc[2][2] = {};
        const int m0 = my * 64, n0 = nx * 64;
        gemm_core_a1b1<64, 64>(A, B, m0, n0, sm.g, acc);
        #pragma unroll
        for (int i = 0; i < 2; i++) {
            int m = m0 + wm * 32 + i * 16 + q * 4;
            #pragma unroll
            for (int j = 0; j < 2; j++) {
                int n = n0 + wn * 32 + j * 16 + fr;
                float bv = bias[n];
                #pragma unroll
                for (int r = 0; r < 4; r++)
                    out[(size_t)(b * 2048 + m + r) * 512 + n] = acc[i][j][r] + bv;
            }
        }
    }
}

// ---------------------------------------------------------------------------
extern "C" void kernel_launch(void* const* d_in, const int* in_sizes, int n_in,
                              void* d_out, int out_size, void* d_ws, size_t ws_size,
                              hipStream_t stream) {
    (void)in_sizes; (void)n_in; (void)out_size; (void)ws_size;
    const float* x1        = (const float*)d_in[0];
    const float* x2        = (const float*)d_in[1];
    const float* gamma     = (const float*)d_in[2];
    const float* beta      = (const float*)d_in[3];
    const float* proj      = (const float*)d_in[4];
    const float* halves    = (const float*)d_in[5];
    const float* diagonals = (const float*)d_in[6];
    const float* Wm        = (const float*)d_in[7];
    const float* bmix      = (const float*)d_in[8];
    float* out = (float*)d_out;

    u16* us    = (u16*)d_ws;
    u16* Xh    = us;                        // 4,194,304
    u16* Pwh   = Xh + 4194304;              // 262,144
    u16* PPh   = Pwh + 262144;              // 2,097,152 (x1 rows only, natural)
    u16* PPT1h = PPh + 2097152;             // 2,097,152 ([b][c][v])
    u16* PPT2h = PPT1h + 2097152;           // 2,097,152
    u16* UTh   = PPT2h + 2097152;           // 524,288
    float* S   = (float*)(UTh + 524288);    // 65,536 f
    unsigned* cnt = (unsigned*)(S + 65536); // 8 u32 barrier counters

    ln_prep<<<dim3(8256), 256, 0, stream>>>(x1, x2, gamma, beta, proj, Xh, Pwh, cnt);
    mega<<<dim3(512), 256, 0, stream>>>(Xh, Pwh, PPh, PPT1h, PPT2h, S,
                                        halves, diagonals, Wm, UTh, bmix, out, cnt);
}

// Round 8
// 127.826 us; speedup vs baseline: 4.2162x; 4.2162x over previous
//
#include <hip/hip_runtime.h>

typedef unsigned short u16;
typedef __attribute__((ext_vector_type(8))) short short8;   // 8 x bf16 (4 VGPRs)
typedef __attribute__((ext_vector_type(4))) float f32x4;

#define HALFN 2016

__device__ __forceinline__ u16 f2b_rn(float x) {         // round-nearest-even
    union { float f; unsigned u; } v; v.f = x;
    unsigned r = v.u + 0x7FFFu + ((v.u >> 16) & 1u);
    return (u16)(r >> 16);
}

__device__ __forceinline__ void gll16(const void* g, void* s) {
    __builtin_amdgcn_global_load_lds(
        (const __attribute__((address_space(1))) unsigned int*)g,
        (__attribute__((address_space(3))) unsigned int*)s, 16, 0, 0);
}

// ---------------------------------------------------------------------------
// Kernel 1: blocks 0..8191 LayerNorm -> Xh (RN bf16);
// blocks 8192..8255 prep Pw (transpose, RN bf16); block 8256 zeroes S.
// ---------------------------------------------------------------------------
__global__ __launch_bounds__(256) void ln_prep(const float* __restrict__ x1,
                                               const float* __restrict__ x2,
                                               const float* __restrict__ gamma,
                                               const float* __restrict__ beta,
                                               const float* __restrict__ proj,
                                               u16* __restrict__ Xh,
                                               u16* __restrict__ Pwh,
                                               float* __restrict__ S) {
    __shared__ float ls[8], lq[8];
    __shared__ float tile[64][65];
    const int bid = blockIdx.x, t = threadIdx.x;

    if (bid < 8192) {
        const float* src = (bid < 4096) ? (x1 + (size_t)bid * 512)
                                        : (x2 + (size_t)(bid - 4096) * 512);
        float2 v = *(const float2*)&src[t * 2];
        float s  = v.x + v.y;
        float sq = v.x * v.x + v.y * v.y;
        #pragma unroll
        for (int off = 32; off > 0; off >>= 1) {
            s  += __shfl_down(s, off);
            sq += __shfl_down(sq, off);
        }
        int wave = t >> 6, lane = t & 63;
        if (lane == 0) { ls[wave] = s; lq[wave] = sq; }
        __syncthreads();
        if (t == 0) {
            float Sm = 0.f, Q = 0.f;
            #pragma unroll
            for (int i = 0; i < 4; i++) { Sm += ls[i]; Q += lq[i]; }
            float mu  = Sm * (1.0f / 512.0f);
            float var = Q * (1.0f / 512.0f) - mu * mu;
            ls[4] = mu;
            lq[4] = rsqrtf(var + 1e-5f);
        }
        __syncthreads();
        float mu = ls[4], rs = lq[4];
        float2 g  = *(const float2*)&gamma[t * 2];
        float2 bb = *(const float2*)&beta[t * 2];
        float o0 = (v.x - mu) * rs * g.x + bb.x;
        float o1 = (v.y - mu) * rs * g.y + bb.y;
        ushort2 H; H.x = f2b_rn(o0); H.y = f2b_rn(o1);
        *(ushort2*)&Xh[(size_t)bid * 512 + t * 2] = H;
    } else if (bid < 8256) {
        const int id = bid - 8192;
        const int n = id >> 3, c0 = (id & 7) * 64;
        #pragma unroll
        for (int i = 0; i < 4; i++) {
            int flat = i * 256 + t;
            int c = flat >> 4, k4 = (flat & 15) * 4;
            float4 v = *(const float4*)&proj[(size_t)n * 32768 + (size_t)(c0 + c) * 64 + k4];
            tile[c][k4 + 0] = v.x; tile[c][k4 + 1] = v.y;
            tile[c][k4 + 2] = v.z; tile[c][k4 + 3] = v.w;
        }
        __syncthreads();
        #pragma unroll
        for (int i = 0; i < 16; i++) {
            int flat = i * 256 + t;
            int k = flat >> 6, c = flat & 63;
            Pwh[(size_t)(n * 64 + k) * 512 + c0 + c] = f2b_rn(tile[c][k]);
        }
    } else {
        float4 z = {0.f, 0.f, 0.f, 0.f};
        #pragma unroll
        for (int i = 0; i < 64; i++)
            *(float4*)&S[(size_t)(i * 256 + t) * 4] = z;
    }
}

// ---------------------------------------------------------------------------
// MFMA single-product bf16 GEMM core: TMxTN tile, BK=32, K=512, ld=512.
// XOR-swizzled LDS, gll16 staging, conflict-free ds_read_b128 fragments.
// ---------------------------------------------------------------------------
template<int TM, int TN>
__device__ __forceinline__ void gemm_core_a1b1(const u16* __restrict__ A,
                                               const u16* __restrict__ B,
                                               int m0, int n0, u16* lds,
                                               f32x4 (&acc)[TM / 32][TN / 32]) {
    constexpr int MI = TM / 32, NI = TN / 32;
    constexpr int LA = TM * 32;
    const int t = threadIdx.x;
    const int lane = t & 63;
    const int w = t >> 6, wm = w & 1, wn = w >> 1;
    const int fr = lane & 15, q = lane >> 4;

    int aoff[MI], boff[NI];
    #pragma unroll
    for (int i = 0; i < MI; i++) {
        int r = wm * (TM / 2) + i * 16 + fr;
        aoff[i] = r * 32 + ((q ^ ((r >> 1) & 3)) * 8);
    }
    #pragma unroll
    for (int j = 0; j < NI; j++) {
        int r = wn * (TN / 2) + j * 16 + fr;
        boff[j] = r * 32 + ((q ^ ((r >> 1) & 3)) * 8);
    }

    for (int kt = 0; kt < 512; kt += 32) {
        #pragma unroll
        for (int p = 0; p < TM / 64; p++) {
            int o = p * 4096 + t * 16;
            int r = o >> 6;
            int kc = ((o >> 4) & 3) ^ ((r >> 1) & 3);
            gll16(A + (size_t)(m0 + r) * 512 + kt + kc * 8, lds + (o >> 1));
        }
        #pragma unroll
        for (int p = 0; p < TN / 64; p++) {
            int o = p * 4096 + t * 16;
            int r = o >> 6;
            int kc = ((o >> 4) & 3) ^ ((r >> 1) & 3);
            gll16(B + (size_t)(n0 + r) * 512 + kt + kc * 8, lds + LA + (o >> 1));
        }
        __syncthreads();
        short8 af[MI], bf[NI];
        #pragma unroll
        for (int i = 0; i < MI; i++)
            af[i] = *(const short8*)(lds + aoff[i]);
        #pragma unroll
        for (int j = 0; j < NI; j++)
            bf[j] = *(const short8*)(lds + LA + boff[j]);
        #pragma unroll
        for (int i = 0; i < MI; i++)
            #pragma unroll
            for (int j = 0; j < NI; j++)
                acc[i][j] = __builtin_amdgcn_mfma_f32_16x16x32_bf16(af[i], bf[j], acc[i][j], 0, 0, 0);
        __syncthreads();
    }
}

// ---------------------------------------------------------------------------
// Kernel 2: PP = Xn @ Pw (128x64 tiles).  grid (64 m, 8 n): linear id
// = m + 64*n, XCD = m%8 -> all 8 n-tiles of one A-slab share an XCD L2.
// ---------------------------------------------------------------------------
__global__ __launch_bounds__(256) void gemm_proj_mfma(const u16* __restrict__ Xh,
                                                      const u16* __restrict__ Pwh,
                                                      u16* __restrict__ PPh,
                                                      u16* __restrict__ PPT1h,
                                                      u16* __restrict__ PPT2h) {
    __shared__ u16 lds[6144];   // 128*32 + 64*32
    f32x4 acc[4][2] = {};
    const int m0 = blockIdx.x * 128, n0 = blockIdx.y * 64;
    gemm_core_a1b1<128, 64>(Xh, Pwh, m0, n0, lds, acc);
    const int t = threadIdx.x, lane = t & 63, w = t >> 6, wm = w & 1, wn = w >> 1;
    const int fr = lane & 15, q = lane >> 4;
    const int src2 = (m0 >= 4096);
    const int b = (m0 & 4095) >> 11;
    const int v00 = m0 & 2047;
    #pragma unroll
    for (int i = 0; i < 4; i++) {
        int mloc = wm * 64 + i * 16 + q * 4;
        int v = v00 + mloc;
        #pragma unroll
        for (int j = 0; j < 2; j++) {
            int n = n0 + wn * 32 + j * 16 + fr;
            u16 hs[4];
            #pragma unroll
            for (int r = 0; r < 4; r++) hs[r] = f2b_rn(acc[i][j][r]);
            ushort4 hv; hv.x = hs[0]; hv.y = hs[1]; hv.z = hs[2]; hv.w = hs[3];
            if (!src2) {
                #pragma unroll
                for (int r = 0; r < 4; r++)
                    PPh[(size_t)(m0 + mloc + r) * 512 + n] = hs[r];
                *(ushort4*)&PPT1h[((size_t)(b * 512 + n)) * 2048 + v] = hv;
            } else {
                *(ushort4*)&PPT2h[((size_t)(b * 512 + n)) * 2048 + v] = hv;
            }
        }
    }
}

// ---------------------------------------------------------------------------
// Kernel 3: G[b,n] = P2^T P1 via single-product MFMA over K=v.
// grid (16 bn, 16 v-splits of 128).  A=PPT2h rows j, B=PPT1h rows kk, ld=2048.
// ---------------------------------------------------------------------------
__global__ __launch_bounds__(256) void s_kernel(const u16* __restrict__ PPT2h,
                                                const u16* __restrict__ PPT1h,
                                                float* __restrict__ S) {
    __shared__ u16 lds[4096];   // A 64x32 + B 64x32
    const int bn = blockIdx.x, b = bn >> 3, n = bn & 7;
    const u16* A = PPT2h + ((size_t)(b * 512 + n * 64)) * 2048;
    const u16* B = PPT1h + ((size_t)(b * 512 + n * 64)) * 2048;
    const int t = threadIdx.x, lane = t & 63, w = t >> 6, wm = w & 1, wn = w >> 1;
    const int fr = lane & 15, q = lane >> 4;

    int aoff[2], boff[2];
    #pragma unroll
    for (int i = 0; i < 2; i++) {
        int r = wm * 32 + i * 16 + fr;
        aoff[i] = r * 32 + ((q ^ ((r >> 1) & 3)) * 8);
    }
    #pragma unroll
    for (int j = 0; j < 2; j++) {
        int r = wn * 32 + j * 16 + fr;
        boff[j] = r * 32 + ((q ^ ((r >> 1) & 3)) * 8);
    }
    const int o = t * 16;
    const int rr = o >> 6;
    const int kc = ((o >> 4) & 3) ^ ((rr >> 1) & 3);
    const int le = o >> 1;

    f32x4 acc[2][2] = {};
    const int k0 = blockIdx.y * 128;
    for (int kt = k0; kt < k0 + 128; kt += 32) {
        size_t g = (size_t)rr * 2048 + kt + kc * 8;
        gll16(A + g, lds + le);
        gll16(B + g, lds + 2048 + le);
        __syncthreads();
        short8 af[2], bf[2];
        #pragma unroll
        for (int i = 0; i < 2; i++) af[i] = *(const short8*)(lds + aoff[i]);
        #pragma unroll
        for (int j = 0; j < 2; j++) bf[j] = *(const short8*)(lds + 2048 + boff[j]);
        #pragma unroll
        for (int i = 0; i < 2; i++)
            #pragma unroll
            for (int j = 0; j < 2; j++)
                acc[i][j] = __builtin_amdgcn_mfma_f32_16x16x32_bf16(af[i], bf[j], acc[i][j], 0, 0, 0);
        __syncthreads();
    }
    float* Sb = S + (size_t)bn * 4096;
    #pragma unroll
    for (int i = 0; i < 2; i++) {
        int jrow = wm * 32 + i * 16 + q * 4;
        #pragma unroll
        for (int j = 0; j < 2; j++) {
            int kk = wn * 32 + j * 16 + fr;
            #pragma unroll
            for (int r = 0; r < 4; r++)
                atomicAdd(&Sb[(jrow + r) * 64 + kk], acc[i][j][r]);
        }
    }
}

// ---------------------------------------------------------------------------
// Kernel 4 (fused tu_a+tu_b, verified in R7 mega): build M, T = M@G in LDS,
// U-chunk -> UTh (RN bf16).  grid 128: bn = bid>>3, cy = bid&7.
// ---------------------------------------------------------------------------
__global__ __launch_bounds__(256) void tu_kernel(const float* __restrict__ S,
                                                 const float* __restrict__ halves,
                                                 const float* __restrict__ diagonals,
                                                 const float* __restrict__ Wm,
                                                 u16* __restrict__ UTh) {
    __shared__ float Ms[64][65];
    __shared__ float Gs[64][68];
    __shared__ float Ts[64][68];
    const int bid = blockIdx.x, t = threadIdx.x;
    const int bn = bid >> 3, b = bn >> 3, n = bn & 7, cy = bid & 7;

    for (int idx = t; idx < 4096; idx += 256) {
        int r = idx >> 6, c = idx & 63;
        float val;
        if (r == c) {
            val = diagonals[n * 64 + r];
        } else {
            int rr = (r < c) ? r : c;
            int cc = (r < c) ? c : r;
            int h = rr * 63 - (rr * (rr - 1)) / 2 + (cc - rr - 1);
            val = halves[n * HALFN + h];
        }
        Ms[r][c] = val;
    }
    for (int idx = t; idx < 4096; idx += 256)
        Gs[idx >> 6][idx & 63] = S[(size_t)bn * 4096 + idx];
    __syncthreads();

    {   // T = M @ G : thread (k = t&63) computes chunk lq = t>>6 (16 cols)
        const int k = t & 63, lq = t >> 6;
        float a[16] = {};
        for (int j = 0; j < 64; j++) {
            float m = Ms[k][j];
            const float* gp = &Gs[j][lq * 16];
            #pragma unroll
            for (int u4 = 0; u4 < 4; u4++) {
                float4 g4 = *(const float4*)&gp[u4 * 4];
                a[u4 * 4 + 0] = fmaf(m, g4.x, a[u4 * 4 + 0]);
                a[u4 * 4 + 1] = fmaf(m, g4.y, a[u4 * 4 + 1]);
                a[u4 * 4 + 2] = fmaf(m, g4.z, a[u4 * 4 + 2]);
                a[u4 * 4 + 3] = fmaf(m, g4.w, a[u4 * 4 + 3]);
            }
        }
        int pos = (lq ^ (k & 3)) * 16;             // swizzled chunk slot
        #pragma unroll
        for (int u4 = 0; u4 < 4; u4++) {
            float4 v4 = {a[u4 * 4 + 0], a[u4 * 4 + 1], a[u4 * 4 + 2], a[u4 * 4 + 3]};
            *(float4*)&Ts[k][pos + u4 * 4] = v4;
        }
    }
    __syncthreads();

    const int k2 = t & 63, cgp = t >> 6;
    const int c0 = cy * 64 + cgp * 16;
    float uacc[16] = {};
    #pragma unroll
    for (int kkc = 0; kkc < 4; kkc++) {
        const float* tp = &Ts[k2][(kkc ^ (k2 & 3)) * 16];
        float ts[16];
        #pragma unroll
        for (int u = 0; u < 4; u++) {
            float4 t4 = *(const float4*)&tp[u * 4];
            ts[u * 4 + 0] = t4.x; ts[u * 4 + 1] = t4.y;
            ts[u * 4 + 2] = t4.z; ts[u * 4 + 3] = t4.w;
        }
        #pragma unroll
        for (int i = 0; i < 16; i++) {
            const float* wrow = &Wm[(size_t)(c0 + i) * 512 + n * 64 + kkc * 16];
            #pragma unroll
            for (int u = 0; u < 4; u++) {
                float4 w4 = *(const float4*)&wrow[u * 4];
                uacc[i] = fmaf(ts[u * 4 + 0], w4.x, uacc[i]);
                uacc[i] = fmaf(ts[u * 4 + 1], w4.y, uacc[i]);
                uacc[i] = fmaf(ts[u * 4 + 2], w4.z, uacc[i]);
                uacc[i] = fmaf(ts[u * 4 + 3], w4.w, uacc[i]);
            }
        }
    }
    #pragma unroll
    for (int i = 0; i < 16; i++)
        UTh[(size_t)b * 262144 + (size_t)(c0 + i) * 512 + n * 64 + k2] = f2b_rn(uacc[i]);
}

// ---------------------------------------------------------------------------
// Kernel 5: out[b] = PP1[b] @ Ucat[b] + b_mixer.  64x64 tiles.
// grid (32 m, 8 n, 2 b): XCD = m%8 -> A-slab reuse within an XCD L2.
// ---------------------------------------------------------------------------
__global__ __launch_bounds__(256) void gemm_out_mfma(const u16* __restrict__ PPh,
                                                     const u16* __restrict__ UTh,
                                                     const float* __restrict__ bias,
                                                     float* __restrict__ out) {
    __shared__ u16 lds[4096];   // A 64x32 + B 64x32
    const int b = blockIdx.z;
    const u16* A = PPh + (size_t)b * 2048 * 512;
    const u16* B = UTh + (size_t)b * 512 * 512;
    f32x4 acc[2][2] = {};
    const int m0 = blockIdx.x * 64, n0 = blockIdx.y * 64;
    gemm_core_a1b1<64, 64>(A, B, m0, n0, lds, acc);
    const int t = threadIdx.x, lane = t & 63, w = t >> 6, wm = w & 1, wn = w >> 1;
    const int fr = lane & 15, q = lane >> 4;
    #pragma unroll
    for (int i = 0; i < 2; i++) {
        int m = m0 + wm * 32 + i * 16 + q * 4;
        #pragma unroll
        for (int j = 0; j < 2; j++) {
            int n = n0 + wn * 32 + j * 16 + fr;
            float bv = bias[n];
            #pragma unroll
            for (int r = 0; r < 4; r++)
                out[(size_t)(b * 2048 + m + r) * 512 + n] = acc[i][j][r] + bv;
        }
    }
}

// ---------------------------------------------------------------------------
extern "C" void kernel_launch(void* const* d_in, const int* in_sizes, int n_in,
                              void* d_out, int out_size, void* d_ws, size_t ws_size,
                              hipStream_t stream) {
    (void)in_sizes; (void)n_in; (void)out_size; (void)ws_size;
    const float* x1        = (const float*)d_in[0];
    const float* x2        = (const float*)d_in[1];
    const float* gamma     = (const float*)d_in[2];
    const float* beta      = (const float*)d_in[3];
    const float* proj      = (const float*)d_in[4];
    const float* halves    = (const float*)d_in[5];
    const float* diagonals = (const float*)d_in[6];
    const float* Wm        = (const float*)d_in[7];
    const float* bmix      = (const float*)d_in[8];
    float* out = (float*)d_out;

    u16* us    = (u16*)d_ws;
    u16* Xh    = us;                        // 4,194,304
    u16* Pwh   = Xh + 4194304;              // 262,144
    u16* PPh   = Pwh + 262144;              // 2,097,152 (x1 rows only, natural)
    u16* PPT1h = PPh + 2097152;             // 2,097,152 ([b][c][v])
    u16* PPT2h = PPT1h + 2097152;           // 2,097,152
    u16* UTh   = PPT2h + 2097152;           // 524,288
    float* S   = (float*)(UTh + 524288);    // 65,536 f

    ln_prep<<<dim3(8257), 256, 0, stream>>>(x1, x2, gamma, beta, proj, Xh, Pwh, S);
    gemm_proj_mfma<<<dim3(64, 8), 256, 0, stream>>>(Xh, Pwh, PPh, PPT1h, PPT2h);
    s_kernel<<<dim3(16, 16), 256, 0, stream>>>(PPT2h, PPT1h, S);
    tu_kernel<<<dim3(128), 256, 0, stream>>>(S, halves, diagonals, Wm, UTh);
    gemm_out_mfma<<<dim3(32, 8, 2), 256, 0, stream>>>(PPh, UTh, bmix, out);
}

// Round 9
// 124.121 us; speedup vs baseline: 4.3420x; 1.0299x over previous
//
#include <hip/hip_runtime.h>

typedef unsigned short u16;
typedef __attribute__((ext_vector_type(8))) short short8;   // 8 x bf16 (4 VGPRs)
typedef __attribute__((ext_vector_type(4))) float f32x4;

#define HALFN 2016

__device__ __forceinline__ u16 f2b_rn(float x) {         // round-nearest-even
    union { float f; unsigned u; } v; v.f = x;
    unsigned r = v.u + 0x7FFFu + ((v.u >> 16) & 1u);
    return (u16)(r >> 16);
}

__device__ __forceinline__ void gll16(const void* g, void* s) {
    __builtin_amdgcn_global_load_lds(
        (const __attribute__((address_space(1))) unsigned int*)g,
        (__attribute__((address_space(3))) unsigned int*)s, 16, 0, 0);
}

// ---------------------------------------------------------------------------
// Kernel 1: blocks 0..2047: LayerNorm, one wave per row (4 rows/block);
// blocks 2048..2111: prep Pw (transpose, RN bf16); block 2112 zeroes S.
// ---------------------------------------------------------------------------
__global__ __launch_bounds__(256) void ln_prep(const float* __restrict__ x1,
                                               const float* __restrict__ x2,
                                               const float* __restrict__ gamma,
                                               const float* __restrict__ beta,
                                               const float* __restrict__ proj,
                                               u16* __restrict__ Xh,
                                               u16* __restrict__ Pwh,
                                               float* __restrict__ S) {
    const int bid = blockIdx.x, t = threadIdx.x;

    if (bid < 2048) {
        const int wv = t >> 6, lane = t & 63;
        const int row = bid * 4 + wv;             // 0..8191
        const float* src = (row < 4096) ? (x1 + (size_t)row * 512)
                                        : (x2 + (size_t)(row - 4096) * 512);
        float4 v0 = *(const float4*)&src[lane * 4];
        float4 v1 = *(const float4*)&src[256 + lane * 4];
        float s  = v0.x + v0.y + v0.z + v0.w + v1.x + v1.y + v1.z + v1.w;
        float sq = v0.x * v0.x + v0.y * v0.y + v0.z * v0.z + v0.w * v0.w +
                   v1.x * v1.x + v1.y * v1.y + v1.z * v1.z + v1.w * v1.w;
        #pragma unroll
        for (int off = 32; off > 0; off >>= 1) {
            s  += __shfl_down(s, off);
            sq += __shfl_down(sq, off);
        }
        s  = __shfl(s, 0);
        sq = __shfl(sq, 0);
        float mu  = s * (1.0f / 512.0f);
        float var = sq * (1.0f / 512.0f) - mu * mu;
        float rs  = rsqrtf(var + 1e-5f);
        float4 g0 = *(const float4*)&gamma[lane * 4];
        float4 g1 = *(const float4*)&gamma[256 + lane * 4];
        float4 b0 = *(const float4*)&beta[lane * 4];
        float4 b1 = *(const float4*)&beta[256 + lane * 4];
        ushort4 h0, h1;
        h0.x = f2b_rn((v0.x - mu) * rs * g0.x + b0.x);
        h0.y = f2b_rn((v0.y - mu) * rs * g0.y + b0.y);
        h0.z = f2b_rn((v0.z - mu) * rs * g0.z + b0.z);
        h0.w = f2b_rn((v0.w - mu) * rs * g0.w + b0.w);
        h1.x = f2b_rn((v1.x - mu) * rs * g1.x + b1.x);
        h1.y = f2b_rn((v1.y - mu) * rs * g1.y + b1.y);
        h1.z = f2b_rn((v1.z - mu) * rs * g1.z + b1.z);
        h1.w = f2b_rn((v1.w - mu) * rs * g1.w + b1.w);
        *(ushort4*)&Xh[(size_t)row * 512 + lane * 4] = h0;
        *(ushort4*)&Xh[(size_t)row * 512 + 256 + lane * 4] = h1;
    } else if (bid < 2112) {
        __shared__ float tile[64][65];
        const int id = bid - 2048;
        const int n = id >> 3, c0 = (id & 7) * 64;
        #pragma unroll
        for (int i = 0; i < 4; i++) {
            int flat = i * 256 + t;
            int c = flat >> 4, k4 = (flat & 15) * 4;
            float4 v = *(const float4*)&proj[(size_t)n * 32768 + (size_t)(c0 + c) * 64 + k4];
            tile[c][k4 + 0] = v.x; tile[c][k4 + 1] = v.y;
            tile[c][k4 + 2] = v.z; tile[c][k4 + 3] = v.w;
        }
        __syncthreads();
        #pragma unroll
        for (int i = 0; i < 16; i++) {
            int flat = i * 256 + t;
            int k = flat >> 6, c = flat & 63;
            Pwh[(size_t)(n * 64 + k) * 512 + c0 + c] = f2b_rn(tile[c][k]);
        }
    } else {
        float4 z = {0.f, 0.f, 0.f, 0.f};
        #pragma unroll
        for (int i = 0; i < 64; i++)
            *(float4*)&S[(size_t)(i * 256 + t) * 4] = z;
    }
}

// ---------------------------------------------------------------------------
// MFMA bf16 GEMM core, BK=64: TMxTN tile, K=512.  LDS rows = 128 B (8 chunks
// of 16 B), XOR swizzle keyed on (row&7) -> even 8-lane/window b128 reads.
// Half the barriers of the BK=32 core at the same gll16 count.
// ---------------------------------------------------------------------------
template<int TM, int TN>
__device__ __forceinline__ void gemm_core_bk64(const u16* __restrict__ A,
                                               const u16* __restrict__ B,
                                               int m0, int n0, int ld, u16* lds,
                                               f32x4 (&acc)[TM / 32][TN / 32]) {
    constexpr int MI = TM / 32, NI = TN / 32;
    constexpr int LA = TM * 64;                  // elems in A tile
    const int t = threadIdx.x;
    const int lane = t & 63;
    const int w = t >> 6, wm = w & 1, wn = w >> 1;
    const int fr = lane & 15, q = lane >> 4;

    int aoff[2][MI], boff[2][NI];
    #pragma unroll
    for (int kc = 0; kc < 2; kc++) {
        #pragma unroll
        for (int i = 0; i < MI; i++) {
            int r = wm * (TM / 2) + i * 16 + fr;
            aoff[kc][i] = r * 64 + (((kc * 4 + q) ^ (r & 7)) * 8);
        }
        #pragma unroll
        for (int j = 0; j < NI; j++) {
            int r = wn * (TN / 2) + j * 16 + fr;
            boff[kc][j] = r * 64 + (((kc * 4 + q) ^ (r & 7)) * 8);
        }
    }

    for (int kt = 0; kt < 512; kt += 64) {
        #pragma unroll
        for (int p = 0; p < TM / 32; p++) {      // A: TM*128 B / 4096 B
            int o = p * 4096 + t * 16;
            int r = o >> 7;
            int c = ((o >> 4) & 7) ^ (r & 7);
            gll16(A + (size_t)(m0 + r) * ld + kt + c * 8, lds + (o >> 1));
        }
        #pragma unroll
        for (int p = 0; p < TN / 32; p++) {      // B
            int o = p * 4096 + t * 16;
            int r = o >> 7;
            int c = ((o >> 4) & 7) ^ (r & 7);
            gll16(B + (size_t)(n0 + r) * ld + kt + c * 8, lds + LA + (o >> 1));
        }
        __syncthreads();
        #pragma unroll
        for (int kc = 0; kc < 2; kc++) {
            short8 af[MI], bf[NI];
            #pragma unroll
            for (int i = 0; i < MI; i++)
                af[i] = *(const short8*)(lds + aoff[kc][i]);
            #pragma unroll
            for (int j = 0; j < NI; j++)
                bf[j] = *(const short8*)(lds + LA + boff[kc][j]);
            #pragma unroll
            for (int i = 0; i < MI; i++)
                #pragma unroll
                for (int j = 0; j < NI; j++)
                    acc[i][j] = __builtin_amdgcn_mfma_f32_16x16x32_bf16(af[i], bf[j], acc[i][j], 0, 0, 0);
        }
        __syncthreads();
    }
}

// ---------------------------------------------------------------------------
// Kernel 2: PP = Xn @ Pw (128x64 tiles).  grid (64 m, 8 n): linear id
// = m + 64*n, XCD = m%8 -> all 8 n-tiles of one A-slab share an XCD L2.
// ---------------------------------------------------------------------------
__global__ __launch_bounds__(256) void gemm_proj_mfma(const u16* __restrict__ Xh,
                                                      const u16* __restrict__ Pwh,
                                                      u16* __restrict__ PPh,
                                                      u16* __restrict__ PPT1h,
                                                      u16* __restrict__ PPT2h) {
    __shared__ u16 lds[12288];   // 128*64 + 64*64
    f32x4 acc[4][2] = {};
    const int m0 = blockIdx.x * 128, n0 = blockIdx.y * 64;
    gemm_core_bk64<128, 64>(Xh, Pwh, m0, n0, 512, lds, acc);
    const int t = threadIdx.x, lane = t & 63, w = t >> 6, wm = w & 1, wn = w >> 1;
    const int fr = lane & 15, q = lane >> 4;
    const int src2 = (m0 >= 4096);
    const int b = (m0 & 4095) >> 11;
    const int v00 = m0 & 2047;
    #pragma unroll
    for (int i = 0; i < 4; i++) {
        int mloc = wm * 64 + i * 16 + q * 4;
        int v = v00 + mloc;
        #pragma unroll
        for (int j = 0; j < 2; j++) {
            int n = n0 + wn * 32 + j * 16 + fr;
            u16 hs[4];
            #pragma unroll
            for (int r = 0; r < 4; r++) hs[r] = f2b_rn(acc[i][j][r]);
            ushort4 hv; hv.x = hs[0]; hv.y = hs[1]; hv.z = hs[2]; hv.w = hs[3];
            if (!src2) {
                #pragma unroll
                for (int r = 0; r < 4; r++)
                    PPh[(size_t)(m0 + mloc + r) * 512 + n] = hs[r];
                *(ushort4*)&PPT1h[((size_t)(b * 512 + n)) * 2048 + v] = hv;
            } else {
                *(ushort4*)&PPT2h[((size_t)(b * 512 + n)) * 2048 + v] = hv;
            }
        }
    }
}

// ---------------------------------------------------------------------------
// Kernel 3: G[b,n] = P2^T P1 via single-product MFMA over K=v.
// grid (16 bn, 16 v-splits of 128).  A=PPT2h rows j, B=PPT1h rows kk, ld=2048.
// (unchanged from R8 — BK=32 XOR swizzle keyed on (r>>1)&3)
// ---------------------------------------------------------------------------
__global__ __launch_bounds__(256) void s_kernel(const u16* __restrict__ PPT2h,
                                                const u16* __restrict__ PPT1h,
                                                float* __restrict__ S) {
    __shared__ u16 lds[4096];   // A 64x32 + B 64x32
    const int bn = blockIdx.x, b = bn >> 3, n = bn & 7;
    const u16* A = PPT2h + ((size_t)(b * 512 + n * 64)) * 2048;
    const u16* B = PPT1h + ((size_t)(b * 512 + n * 64)) * 2048;
    const int t = threadIdx.x, lane = t & 63, w = t >> 6, wm = w & 1, wn = w >> 1;
    const int fr = lane & 15, q = lane >> 4;

    int aoff[2], boff[2];
    #pragma unroll
    for (int i = 0; i < 2; i++) {
        int r = wm * 32 + i * 16 + fr;
        aoff[i] = r * 32 + ((q ^ ((r >> 1) & 3)) * 8);
    }
    #pragma unroll
    for (int j = 0; j < 2; j++) {
        int r = wn * 32 + j * 16 + fr;
        boff[j] = r * 32 + ((q ^ ((r >> 1) & 3)) * 8);
    }
    const int o = t * 16;
    const int rr = o >> 6;
    const int kc = ((o >> 4) & 3) ^ ((rr >> 1) & 3);
    const int le = o >> 1;

    f32x4 acc[2][2] = {};
    const int k0 = blockIdx.y * 128;
    for (int kt = k0; kt < k0 + 128; kt += 32) {
        size_t g = (size_t)rr * 2048 + kt + kc * 8;
        gll16(A + g, lds + le);
        gll16(B + g, lds + 2048 + le);
        __syncthreads();
        short8 af[2], bf[2];
        #pragma unroll
        for (int i = 0; i < 2; i++) af[i] = *(const short8*)(lds + aoff[i]);
        #pragma unroll
        for (int j = 0; j < 2; j++) bf[j] = *(const short8*)(lds + 2048 + boff[j]);
        #pragma unroll
        for (int i = 0; i < 2; i++)
            #pragma unroll
            for (int j = 0; j < 2; j++)
                acc[i][j] = __builtin_amdgcn_mfma_f32_16x16x32_bf16(af[i], bf[j], acc[i][j], 0, 0, 0);
        __syncthreads();
    }
    float* Sb = S + (size_t)bn * 4096;
    #pragma unroll
    for (int i = 0; i < 2; i++) {
        int jrow = wm * 32 + i * 16 + q * 4;
        #pragma unroll
        for (int j = 0; j < 2; j++) {
            int kk = wn * 32 + j * 16 + fr;
            #pragma unroll
            for (int r = 0; r < 4; r++)
                atomicAdd(&Sb[(jrow + r) * 64 + kk], acc[i][j][r]);
        }
    }
}

// ---------------------------------------------------------------------------
// Kernel 4 (fused tu): build M, T = M@G in LDS, U-chunk -> UTh (RN bf16).
// grid 128: bn = bid>>3, cy = bid&7.  (unchanged from R8)
// ---------------------------------------------------------------------------
__global__ __launch_bounds__(256) void tu_kernel(const float* __restrict__ S,
                                                 const float* __restrict__ halves,
                                                 const float* __restrict__ diagonals,
                                                 const float* __restrict__ Wm,
                                                 u16* __restrict__ UTh) {
    __shared__ float Ms[64][65];
    __shared__ float Gs[64][68];
    __shared__ float Ts[64][68];
    const int bid = blockIdx.x, t = threadIdx.x;
    const int bn = bid >> 3, b = bn >> 3, n = bn & 7, cy = bid & 7;

    for (int idx = t; idx < 4096; idx += 256) {
        int r = idx >> 6, c = idx & 63;
        float val;
        if (r == c) {
            val = diagonals[n * 64 + r];
        } else {
            int rr = (r < c) ? r : c;
            int cc = (r < c) ? c : r;
            int h = rr * 63 - (rr * (rr - 1)) / 2 + (cc - rr - 1);
            val = halves[n * HALFN + h];
        }
        Ms[r][c] = val;
    }
    for (int idx = t; idx < 4096; idx += 256)
        Gs[idx >> 6][idx & 63] = S[(size_t)bn * 4096 + idx];
    __syncthreads();

    {   // T = M @ G : thread (k = t&63) computes chunk lq = t>>6 (16 cols)
        const int k = t & 63, lq = t >> 6;
        float a[16] = {};
        for (int j = 0; j < 64; j++) {
            float m = Ms[k][j];
            const float* gp = &Gs[j][lq * 16];
            #pragma unroll
            for (int u4 = 0; u4 < 4; u4++) {
                float4 g4 = *(const float4*)&gp[u4 * 4];
                a[u4 * 4 + 0] = fmaf(m, g4.x, a[u4 * 4 + 0]);
                a[u4 * 4 + 1] = fmaf(m, g4.y, a[u4 * 4 + 1]);
                a[u4 * 4 + 2] = fmaf(m, g4.z, a[u4 * 4 + 2]);
                a[u4 * 4 + 3] = fmaf(m, g4.w, a[u4 * 4 + 3]);
            }
        }
        int pos = (lq ^ (k & 3)) * 16;             // swizzled chunk slot
        #pragma unroll
        for (int u4 = 0; u4 < 4; u4++) {
            float4 v4 = {a[u4 * 4 + 0], a[u4 * 4 + 1], a[u4 * 4 + 2], a[u4 * 4 + 3]};
            *(float4*)&Ts[k][pos + u4 * 4] = v4;
        }
    }
    __syncthreads();

    const int k2 = t & 63, cgp = t >> 6;
    const int c0 = cy * 64 + cgp * 16;
    float uacc[16] = {};
    #pragma unroll
    for (int kkc = 0; kkc < 4; kkc++) {
        const float* tp = &Ts[k2][(kkc ^ (k2 & 3)) * 16];
        float ts[16];
        #pragma unroll
        for (int u = 0; u < 4; u++) {
            float4 t4 = *(const float4*)&tp[u * 4];
            ts[u * 4 + 0] = t4.x; ts[u * 4 + 1] = t4.y;
            ts[u * 4 + 2] = t4.z; ts[u * 4 + 3] = t4.w;
        }
        #pragma unroll
        for (int i = 0; i < 16; i++) {
            const float* wrow = &Wm[(size_t)(c0 + i) * 512 + n * 64 + kkc * 16];
            #pragma unroll
            for (int u = 0; u < 4; u++) {
                float4 w4 = *(const float4*)&wrow[u * 4];
                uacc[i] = fmaf(ts[u * 4 + 0], w4.x, uacc[i]);
                uacc[i] = fmaf(ts[u * 4 + 1], w4.y, uacc[i]);
                uacc[i] = fmaf(ts[u * 4 + 2], w4.z, uacc[i]);
                uacc[i] = fmaf(ts[u * 4 + 3], w4.w, uacc[i]);
            }
        }
    }
    #pragma unroll
    for (int i = 0; i < 16; i++)
        UTh[(size_t)b * 262144 + (size_t)(c0 + i) * 512 + n * 64 + k2] = f2b_rn(uacc[i]);
}

// ---------------------------------------------------------------------------
// Kernel 5: out[b] = PP1[b] @ Ucat[b] + b_mixer.  64x64 tiles, BK=64 core.
// grid (32 m, 8 n, 2 b): XCD = m%8 -> A-slab reuse within an XCD L2.
// ---------------------------------------------------------------------------
__global__ __launch_bounds__(256) void gemm_out_mfma(const u16* __restrict__ PPh,
                                                     const u16* __restrict__ UTh,
                                                     const float* __restrict__ bias,
                                                     float* __restrict__ out) {
    __shared__ u16 lds[8192];   // A 64x64 + B 64x64
    const int b = blockIdx.z;
    const u16* A = PPh + (size_t)b * 2048 * 512;
    const u16* B = UTh + (size_t)b * 512 * 512;
    f32x4 acc[2][2] = {};
    const int m0 = blockIdx.x * 64, n0 = blockIdx.y * 64;
    gemm_core_bk64<64, 64>(A, B, m0, n0, 512, lds, acc);
    const int t = threadIdx.x, lane = t & 63, w = t >> 6, wm = w & 1, wn = w >> 1;
    const int fr = lane & 15, q = lane >> 4;
    #pragma unroll
    for (int i = 0; i < 2; i++) {
        int m = m0 + wm * 32 + i * 16 + q * 4;
        #pragma unroll
        for (int j = 0; j < 2; j++) {
            int n = n0 + wn * 32 + j * 16 + fr;
            float bv = bias[n];
            #pragma unroll
            for (int r = 0; r < 4; r++)
                out[(size_t)(b * 2048 + m + r) * 512 + n] = acc[i][j][r] + bv;
        }
    }
}

// ---------------------------------------------------------------------------
extern "C" void kernel_launch(void* const* d_in, const int* in_sizes, int n_in,
                              void* d_out, int out_size, void* d_ws, size_t ws_size,
                              hipStream_t stream) {
    (void)in_sizes; (void)n_in; (void)out_size; (void)ws_size;
    const float* x1        = (const float*)d_in[0];
    const float* x2        = (const float*)d_in[1];
    const float* gamma     = (const float*)d_in[2];
    const float* beta      = (const float*)d_in[3];
    const float* proj      = (const float*)d_in[4];
    const float* halves    = (const float*)d_in[5];
    const float* diagonals = (const float*)d_in[6];
    const float* Wm        = (const float*)d_in[7];
    const float* bmix      = (const float*)d_in[8];
    float* out = (float*)d_out;

    u16* us    = (u16*)d_ws;
    u16* Xh    = us;                        // 4,194,304
    u16* Pwh   = Xh + 4194304;              // 262,144
    u16* PPh   = Pwh + 262144;              // 2,097,152 (x1 rows only, natural)
    u16* PPT1h = PPh + 2097152;             // 2,097,152 ([b][c][v])
    u16* PPT2h = PPT1h + 2097152;           // 2,097,152
    u16* UTh   = PPT2h + 2097152;           // 524,288
    float* S   = (float*)(UTh + 524288);    // 65,536 f

    ln_prep<<<dim3(2113), 256, 0, stream>>>(x1, x2, gamma, beta, proj, Xh, Pwh, S);
    gemm_proj_mfma<<<dim3(64, 8), 256, 0, stream>>>(Xh, Pwh, PPh, PPT1h, PPT2h);
    s_kernel<<<dim3(16, 16), 256, 0, stream>>>(PPT2h, PPT1h, S);
    tu_kernel<<<dim3(128), 256, 0, stream>>>(S, halves, diagonals, Wm, UTh);
    gemm_out_mfma<<<dim3(32, 8, 2), 256, 0, stream>>>(PPh, UTh, bmix, out);
}